// Round 5
// baseline (222.674 us; speedup 1.0000x reference)
//
#include <hip/hip_runtime.h>
#include <hip/hip_fp16.h>
#include <math.h>

// ---------------------------------------------------------------------------
// Fused transformer block: QKV proj -> masked MHA -> out proj + residual -> LN
// B=2, S=2048, D=1024, H=16, hd=64.  All GEMM/attention compute in fp16 MFMA
// with fp32 accumulation; final output fp32.
// ---------------------------------------------------------------------------

typedef _Float16 half8 __attribute__((ext_vector_type(8)));
typedef _Float16 half4v __attribute__((ext_vector_type(4)));
typedef float f32x4 __attribute__((ext_vector_type(4)));

#define MFMA16(a, b, c) __builtin_amdgcn_mfma_f32_16x16x32_f16((a), (b), (c), 0, 0, 0)

// global -> LDS direct 16B copy (wave-uniform LDS base + lane*16 dest)
typedef __attribute__((address_space(1))) void gas_void;
typedef __attribute__((address_space(3))) void las_void;
static __device__ __forceinline__ void gld16(const void* g, void* l) {
    __builtin_amdgcn_global_load_lds((gas_void*)g, (las_void*)l, 16, 0, 0);
}

// ---------------------------------------------------------------------------
// Mask dtype detection: scan first 2048 words interpreted as int32. If mask is
// int32 (values 0/1) every word is <=1. If mask is 1-byte bool, words pack 4
// bytes of 0/1 -> some word >1 with probability 1 - 8^-2048.
// ---------------------------------------------------------------------------
__global__ void mask_detect_kernel(const unsigned int* __restrict__ m, int* __restrict__ flag) {
    __shared__ int any;
    if (threadIdx.x == 0) any = 0;
    __syncthreads();
    unsigned v = 0;
#pragma unroll
    for (int i = 0; i < 8; ++i) v |= m[threadIdx.x + i * 256];
    if (v > 1u) atomicOr(&any, 1);
    __syncthreads();
    if (threadIdx.x == 0) *flag = any;
}

// mask -> additive fp16 bias (0 or -60000), [B][S][S]
__global__ void mask_bias_kernel(const void* __restrict__ mask, const int* __restrict__ flag,
                                 _Float16* __restrict__ mb) {
    const int i = (blockIdx.x * 256 + threadIdx.x) * 4;
    const bool bytemode = (*flag != 0);
    int v0, v1, v2, v3;
    if (bytemode) {
        const unsigned int w = *(const unsigned int*)((const unsigned char*)mask + i);
        v0 = w & 0xff; v1 = (w >> 8) & 0xff; v2 = (w >> 16) & 0xff; v3 = (w >> 24) & 0xff;
    } else {
        const int4 w = *(const int4*)((const int*)mask + i);
        v0 = w.x; v1 = w.y; v2 = w.z; v3 = w.w;
    }
    const _Float16 NEG = (_Float16)(-60000.0f);
    const _Float16 ZER = (_Float16)(0.0f);
    half4v o = { v0 ? NEG : ZER, v1 ? NEG : ZER, v2 ? NEG : ZER, v3 ? NEG : ZER };
    *(half4v*)(mb + i) = o;
}

// fp32 -> fp16 cast, 4 elems/thread
__global__ void cast_kernel(const float* __restrict__ in, _Float16* __restrict__ out) {
    const int i = (blockIdx.x * 256 + threadIdx.x) * 4;
    const float4 v = *(const float4*)(in + i);
    half4v o = { (_Float16)v.x, (_Float16)v.y, (_Float16)v.z, (_Float16)v.w };
    *(half4v*)(out + i) = o;
}

// W[k][n] fp32 -> Wt[n][k] fp16 (transposed cast), 32x32 tiles
__global__ void wtrans_kernel(const float* __restrict__ W, _Float16* __restrict__ Wt) {
    __shared__ float t[32][33];
    const int tx = threadIdx.x, ty = threadIdx.y;
    const int n0 = blockIdx.x * 32, k0 = blockIdx.y * 32;
#pragma unroll
    for (int i = 0; i < 4; ++i)
        t[ty + i * 8][tx] = W[(size_t)(k0 + ty + i * 8) * 1024 + n0 + tx];
    __syncthreads();
#pragma unroll
    for (int i = 0; i < 4; ++i)
        Wt[(size_t)(n0 + ty + i * 8) * 1024 + k0 + tx] = (_Float16)t[tx][ty + i * 8];
}

// Vh[bh][s][d] -> Vt[bh][d][s], 32x32 tiles
__global__ void vtrans_kernel(const _Float16* __restrict__ Vh, _Float16* __restrict__ Vt) {
    __shared__ _Float16 t[32][33];
    const int tx = threadIdx.x, ty = threadIdx.y;
    const int d0 = blockIdx.x * 32, s0 = blockIdx.y * 32, bh = blockIdx.z;
    const _Float16* src = Vh + (size_t)bh * 2048 * 64;
    _Float16* dst = Vt + (size_t)bh * 64 * 2048;
#pragma unroll
    for (int i = 0; i < 4; ++i)
        t[ty + i * 8][tx] = src[(size_t)(s0 + ty + i * 8) * 64 + d0 + tx];
    __syncthreads();
#pragma unroll
    for (int i = 0; i < 4; ++i)
        dst[(size_t)(d0 + ty + i * 8) * 2048 + s0 + tx] = t[tx][ty + i * 8];
}

// ---------------------------------------------------------------------------
// QKV projection GEMM (m97 structure): grid.z selects q/k/v. 128x128 tile,
// BK=32, 4 waves, global_load_lds width-16 staging, 2 barriers per K-step.
// Epilogue: + bias, write head layout [b,h,s,d] fp16.
// ---------------------------------------------------------------------------
__global__ __launch_bounds__(256) void gemm_qkv_kernel(
    const _Float16* __restrict__ Abase, const _Float16* __restrict__ Btbase,
    const float* __restrict__ bq, const float* __restrict__ bk, const float* __restrict__ bv,
    _Float16* __restrict__ Hbase) {
    constexpr int K = 1024;
    const int z = blockIdx.z;
    const _Float16* A = Abase + (size_t)z * 4096 * 1024;
    const _Float16* Bt = Btbase + (size_t)z * 1024 * 1024;
    const float* bias = (z == 0) ? bq : ((z == 1) ? bk : bv);
    _Float16* outh = Hbase + (size_t)z * 32 * 2048 * 64;

    __shared__ __align__(16) _Float16 As[128 * 32];
    __shared__ __align__(16) _Float16 Bs[128 * 32];
    const int tid = threadIdx.x;
    const int mBase = blockIdx.x * 128, nBase = blockIdx.y * 128;
    const int r0 = tid >> 2, c0 = (tid & 3) * 8;
    const _Float16* gA = A + (size_t)(mBase + r0) * K + c0;
    const _Float16* gB = Bt + (size_t)(nBase + r0) * K + c0;
    const int lane = tid & 63, wid = tid >> 6;
    const int wm = (wid >> 1) * 64, wn = (wid & 1) * 64;
    const int fr = lane & 15, fg = lane >> 4;
    _Float16* lA0 = &As[wid * 512];
    _Float16* lA1 = &As[2048 + wid * 512];
    _Float16* lB0 = &Bs[wid * 512];
    _Float16* lB1 = &Bs[2048 + wid * 512];

    f32x4 acc[4][4] = {};
    for (int kt = 0; kt < K / 32; ++kt) {
        const int kOff = kt * 32;
        gld16(gA + kOff, lA0);
        gld16(gA + 64 * K + kOff, lA1);
        gld16(gB + kOff, lB0);
        gld16(gB + 64 * K + kOff, lB1);
        __syncthreads();   // drains vmcnt before barrier -> tile resident
        half8 af[4], bfv[4];
#pragma unroll
        for (int i = 0; i < 4; ++i) af[i] = *(const half8*)&As[(wm + i * 16 + fr) * 32 + fg * 8];
#pragma unroll
        for (int i = 0; i < 4; ++i) bfv[i] = *(const half8*)&Bs[(wn + i * 16 + fr) * 32 + fg * 8];
#pragma unroll
        for (int mi = 0; mi < 4; ++mi)
#pragma unroll
            for (int ni = 0; ni < 4; ++ni)
                acc[mi][ni] = MFMA16(af[mi], bfv[ni], acc[mi][ni]);
        __syncthreads();   // protect tile from next-iter overwrite
    }
#pragma unroll
    for (int mi = 0; mi < 4; ++mi)
#pragma unroll
        for (int ni = 0; ni < 4; ++ni)
#pragma unroll
            for (int j = 0; j < 4; ++j) {
                const int row = mBase + wm + mi * 16 + fg * 4 + j;  // 0..4095
                const int col = nBase + wn + ni * 16 + fr;          // 0..1023
                const float v = acc[mi][ni][j] + bias[col];
                const int b = row >> 11, s = row & 2047, h = col >> 6, d = col & 63;
                outh[(((size_t)(b * 16 + h) * 2048) + s) * 64 + d] = (_Float16)v;
            }
}

// Output projection GEMM: y = ctx @ Wo + bo + residual (fp32 out).
// Reg-staged dbuf kept: grid is only 256 blocks (1/CU) so the 2-barrier
// global_load_lds drain would be fully exposed here.
__global__ __launch_bounds__(256) void gemm_out_kernel(
    const _Float16* __restrict__ A, const _Float16* __restrict__ Bt,
    const float* __restrict__ bias, const float* __restrict__ resid,
    float* __restrict__ outf) {
    constexpr int K = 1024;
    __shared__ __align__(16) _Float16 As[128 * 32];
    __shared__ __align__(16) _Float16 Bs[128 * 32];
    const int tid = threadIdx.x;
    const int mBase = blockIdx.x * 128, nBase = blockIdx.y * 128;
    const int r0 = tid >> 2, c0 = (tid & 3) * 8;
    const _Float16* gA = A + (size_t)(mBase + r0) * K + c0;
    const _Float16* gB = Bt + (size_t)(nBase + r0) * K + c0;
    const int lane = tid & 63, wid = tid >> 6;
    const int wm = (wid >> 1) * 64, wn = (wid & 1) * 64;
    const int fr = lane & 15, fg = lane >> 4;

    f32x4 acc[4][4] = {};
    half8 ra0 = *(const half8*)(gA);
    half8 ra1 = *(const half8*)(gA + 64 * K);
    half8 rb0 = *(const half8*)(gB);
    half8 rb1 = *(const half8*)(gB + 64 * K);
    for (int kt = 0; kt < K / 32; ++kt) {
        __syncthreads();
        *(half8*)&As[tid * 8] = ra0;
        *(half8*)&As[tid * 8 + 2048] = ra1;
        *(half8*)&Bs[tid * 8] = rb0;
        *(half8*)&Bs[tid * 8 + 2048] = rb1;
        __syncthreads();
        if (kt + 1 < K / 32) {
            const int k1 = (kt + 1) * 32;
            ra0 = *(const half8*)(gA + k1);
            ra1 = *(const half8*)(gA + 64 * K + k1);
            rb0 = *(const half8*)(gB + k1);
            rb1 = *(const half8*)(gB + 64 * K + k1);
        }
        half8 af[4], bfv[4];
#pragma unroll
        for (int i = 0; i < 4; ++i) af[i] = *(const half8*)&As[(wm + i * 16 + fr) * 32 + fg * 8];
#pragma unroll
        for (int i = 0; i < 4; ++i) bfv[i] = *(const half8*)&Bs[(wn + i * 16 + fr) * 32 + fg * 8];
#pragma unroll
        for (int mi = 0; mi < 4; ++mi)
#pragma unroll
            for (int ni = 0; ni < 4; ++ni)
                acc[mi][ni] = MFMA16(af[mi], bfv[ni], acc[mi][ni]);
    }
#pragma unroll
    for (int mi = 0; mi < 4; ++mi)
#pragma unroll
        for (int ni = 0; ni < 4; ++ni)
#pragma unroll
            for (int j = 0; j < 4; ++j) {
                const int row = mBase + wm + mi * 16 + fg * 4 + j;
                const int col = nBase + wn + ni * 16 + fr;
                const size_t idx = (size_t)row * 1024 + col;
                outf[idx] = acc[mi][ni][j] + bias[col] + resid[idx];
            }
}

// ---------------------------------------------------------------------------
// Flash attention v4: v3 staging structure + VALU-diet softmax.
//  - Q fragments pre-scaled by 0.125*log2(e): scores exit MFMA in log2-domain
//    -> per-element work is add(mask) / sub / v_exp_f32 (exp2) only.
//  - l accumulated by a ones-A MFMA riding the PV pipe (same rescaling as
//    acc); removes the 16-add row-sum + 2 shuffles per tile.
//  - defer-max (TH = 11.5 log2-units ~ e^8): cross-lane max reduce + acc
//    rescale only when __any(pmax > m + TH); common path has no shuffles.
//    P bounded by 2^11.5 ~ 2980 (fp16-safe); online rescale self-heals
//    all-masked-prefix tiles (scf = exp2(-big) = 0 zeroes bogus acc & l).
// ---------------------------------------------------------------------------
__global__ __launch_bounds__(256) void attn_kernel(
    const _Float16* __restrict__ Qh, const _Float16* __restrict__ Kh,
    const _Float16* __restrict__ Vt, const _Float16* __restrict__ mb,
    _Float16* __restrict__ ctx) {
    constexpr int S = 2048;
    // [buf][K=0/V=1][64 rows][64 halfs], XOR-swizzled columns. 32 KiB.
    __shared__ __align__(16) _Float16 KVs[2][2][64][64];
    __shared__ __align__(16) _Float16 Pl[4][16][72];  // 64 + 8 pad
    const int tid = threadIdx.x, lane = tid & 63, wid = tid >> 6;
    const int fr = lane & 15, fg = lane >> 4;
    const int bh = blockIdx.y;
    const int b = bh >> 4, h = bh & 15;
    const int q0 = blockIdx.x * 64 + wid * 16;
    const int q = q0 + fr;                     // this lane's q-row everywhere
    const _Float16* Qp = Qh + (size_t)bh * S * 64;
    const _Float16* Kp = Kh + (size_t)bh * S * 64;
    const _Float16* Vp = Vt + (size_t)bh * 64 * S;
    const _Float16* mrow = mb + ((size_t)b * S + q) * S;

    // Q as B-fragment, pre-scaled into log2-domain: 0.125 * log2(e)
    half8 qf0 = *(const half8*)(Qp + (size_t)q * 64 + fg * 8);
    half8 qf1 = *(const half8*)(Qp + (size_t)q * 64 + 32 + fg * 8);
    const _Float16 QSC = (_Float16)0.18033688f;
#pragma unroll
    for (int i = 0; i < 8; ++i) { qf0[i] = qf0[i] * QSC; qf1[i] = qf1[i] * QSC; }
    half8 ones8;
#pragma unroll
    for (int i = 0; i < 8; ++i) ones8[i] = (_Float16)1.0f;

    // staging geometry: thread handles chunks cA=tid, cB=tid+256 of each tile
    const int rA = tid >> 3, rB = (tid >> 3) + 32;
    const int colA = (tid & 7) * 8;                      // halfs
    const int wA = rA * 64 + (colA ^ ((rA & 7) << 3));   // swizzled LDS offset
    const int wB = rB * 64 + (colA ^ ((rB & 7) << 3));
    const int swz = (fr & 7) << 3;                       // read-side swizzle

    f32x4 acc[4] = {};   // acc[n][j] = ctx[q][d = n*16 + fg*4 + j]
    f32x4 accl = {};     // ones-row MFMA: all 4 comps = sum_k P[k][q]
    float m_r = -1e30f;
    const float TH = 11.5f;   // defer-max threshold (log2 units)

    // ---- prologue: stage tile 0 into buf 0, load mask tile 0 ----
    half8 sK0 = *(const half8*)(Kp + (size_t)rA * 64 + colA);
    half8 sK1 = *(const half8*)(Kp + (size_t)rB * 64 + colA);
    half8 sV0 = *(const half8*)(Vp + (size_t)rA * S + colA);
    half8 sV1 = *(const half8*)(Vp + (size_t)rB * S + colA);
    half4v mcur0 = *(const half4v*)(mrow + 0 * 16 + fg * 4);
    half4v mcur1 = *(const half4v*)(mrow + 1 * 16 + fg * 4);
    half4v mcur2 = *(const half4v*)(mrow + 2 * 16 + fg * 4);
    half4v mcur3 = *(const half4v*)(mrow + 3 * 16 + fg * 4);
    *(half8*)&KVs[0][0][0][wA] = sK0;
    *(half8*)&KVs[0][0][0][wB] = sK1;
    *(half8*)&KVs[0][1][0][wA] = sV0;
    *(half8*)&KVs[0][1][0][wB] = sV1;
    __syncthreads();

    for (int t = 0; t < 32; ++t) {
        const int k0 = t * 64;
        const int kn = (t < 31) ? k0 + 64 : k0;   // clamped prefetch target

        // ---- issue next-tile global loads (consumed at bottom) ----
        sK0 = *(const half8*)(Kp + (size_t)(kn + rA) * 64 + colA);
        sK1 = *(const half8*)(Kp + (size_t)(kn + rB) * 64 + colA);
        sV0 = *(const half8*)(Vp + (size_t)rA * S + kn + colA);
        sV1 = *(const half8*)(Vp + (size_t)rB * S + kn + colA);
        half4v mn0 = *(const half4v*)(mrow + kn + 0 * 16 + fg * 4);
        half4v mn1 = *(const half4v*)(mrow + kn + 1 * 16 + fg * 4);
        half4v mn2 = *(const half4v*)(mrow + kn + 2 * 16 + fg * 4);
        half4v mn3 = *(const half4v*)(mrow + kn + 3 * 16 + fg * 4);

        const _Float16* Kb = &KVs[t & 1][0][0][0];
        const _Float16* Vb = &KVs[t & 1][1][0][0];

        // ---- QK^T swapped: A = K rows, B = Q cols -> D[k][q] (log2-domain) ----
        f32x4 tt[4];
#pragma unroll
        for (int s = 0; s < 4; ++s) {
            const int r = s * 16 + fr;
            const half8 ka0 = *(const half8*)&Kb[r * 64 + ((fg * 8) ^ swz)];
            const half8 ka1 = *(const half8*)&Kb[r * 64 + ((32 + fg * 8) ^ swz)];
            f32x4 z = {};
            tt[s] = MFMA16(ka0, qf0, z);
            tt[s] = MFMA16(ka1, qf1, tt[s]);
        }

        // ---- 16 in-lane scores for q: k = k0 + s*16 + fg*4 + j ----
        float p[4][4];
        float pmax = -1e30f;
        {
            const half4v mball[4] = { mcur0, mcur1, mcur2, mcur3 };
#pragma unroll
            for (int s = 0; s < 4; ++s)
#pragma unroll
                for (int j = 0; j < 4; ++j) {
                    p[s][j] = tt[s][j] + (float)mball[s][j];
                    pmax = fmaxf(pmax, p[s][j]);
                }
        }
        // defer-max: only reduce/rescale when the running max is stale
        if (__any(pmax > m_r + TH)) {
            pmax = fmaxf(pmax, __shfl_xor(pmax, 16));
            pmax = fmaxf(pmax, __shfl_xor(pmax, 32));
            const float mnew = fmaxf(m_r, pmax);
            const float scf = exp2f(m_r - mnew);
#pragma unroll
            for (int n = 0; n < 4; ++n)
#pragma unroll
                for (int j = 0; j < 4; ++j) acc[n][j] *= scf;
#pragma unroll
            for (int j = 0; j < 4; ++j) accl[j] *= scf;
            m_r = mnew;
        }
#pragma unroll
        for (int s = 0; s < 4; ++s)
#pragma unroll
            for (int j = 0; j < 4; ++j)
                p[s][j] = exp2f(p[s][j] - m_r);

        // pack P (fp16) -> LDS row q: Pl[wid][fr][k]
#pragma unroll
        for (int s = 0; s < 4; ++s) {
            half4v ph = { (_Float16)p[s][0], (_Float16)p[s][1],
                          (_Float16)p[s][2], (_Float16)p[s][3] };
            *(half4v*)&Pl[wid][fr][s * 16 + fg * 4] = ph;
        }

        // ---- PV swapped: A = Vt rows (d), B = P^T -> D[d][q]; l via ones-A ----
        const half8 pa0 = *(const half8*)&Pl[wid][fr][fg * 8];
        const half8 pa1 = *(const half8*)&Pl[wid][fr][32 + fg * 8];
        accl = MFMA16(ones8, pa0, accl);
        accl = MFMA16(ones8, pa1, accl);
#pragma unroll
        for (int n = 0; n < 4; ++n) {
            const int d = n * 16 + fr;
            const half8 vb0 = *(const half8*)&Vb[d * 64 + ((fg * 8) ^ swz)];
            const half8 vb1 = *(const half8*)&Vb[d * 64 + ((32 + fg * 8) ^ swz)];
            acc[n] = MFMA16(vb0, pa0, acc[n]);
            acc[n] = MFMA16(vb1, pa1, acc[n]);
        }

        // ---- write next tile into the other buffer, advance mask regs ----
        {
            _Float16* Kw = &KVs[(t + 1) & 1][0][0][0];
            _Float16* Vw = &KVs[(t + 1) & 1][1][0][0];
            *(half8*)&Kw[wA] = sK0;
            *(half8*)&Kw[wB] = sK1;
            *(half8*)&Vw[wA] = sV0;
            *(half8*)&Vw[wB] = sV1;
        }
        mcur0 = mn0; mcur1 = mn1; mcur2 = mn2; mcur3 = mn3;
        __syncthreads();
    }

    const float inv = 1.0f / accl[0];
#pragma unroll
    for (int n = 0; n < 4; ++n) {
        half4v o = { (_Float16)(acc[n][0] * inv), (_Float16)(acc[n][1] * inv),
                     (_Float16)(acc[n][2] * inv), (_Float16)(acc[n][3] * inv) };
        *(half4v*)&ctx[((size_t)b * 2048 + q) * 1024 + h * 64 + n * 16 + fg * 4] = o;
    }
}

// LayerNorm over D=1024, one block per row
__global__ __launch_bounds__(256) void ln_kernel(
    const float* __restrict__ y, const float* __restrict__ gamma,
    const float* __restrict__ beta, float* __restrict__ out) {
    const int row = blockIdx.x, tid = threadIdx.x;
    const size_t base = (size_t)row * 1024 + tid * 4;
    const float4 v = *(const float4*)(y + base);
    float s = v.x + v.y + v.z + v.w;
    float ss = v.x * v.x + v.y * v.y + v.z * v.z + v.w * v.w;
#pragma unroll
    for (int o = 1; o < 64; o <<= 1) {
        s += __shfl_xor(s, o, 64);
        ss += __shfl_xor(ss, o, 64);
    }
    __shared__ float red[8];
    const int wid = tid >> 6;
    if ((tid & 63) == 0) { red[wid] = s; red[wid + 4] = ss; }
    __syncthreads();
    s = red[0] + red[1] + red[2] + red[3];
    ss = red[4] + red[5] + red[6] + red[7];
    const float mu = s * (1.0f / 1024.0f);
    const float var = ss * (1.0f / 1024.0f) - mu * mu;
    const float rstd = rsqrtf(var + 1e-5f);
    const float4 g = *(const float4*)(gamma + tid * 4);
    const float4 bt = *(const float4*)(beta + tid * 4);
    float4 o;
    o.x = (v.x - mu) * rstd * g.x + bt.x;
    o.y = (v.y - mu) * rstd * g.y + bt.y;
    o.z = (v.z - mu) * rstd * g.z + bt.z;
    o.w = (v.w - mu) * rstd * g.w + bt.w;
    *(float4*)(out + base) = o;
}

// ---------------------------------------------------------------------------
extern "C" void kernel_launch(void* const* d_in, const int* in_sizes, int n_in,
                              void* d_out, int out_size, void* d_ws, size_t ws_size,
                              hipStream_t stream) {
    (void)in_sizes; (void)n_in; (void)out_size; (void)ws_size;
    const float* q     = (const float*)d_in[0];
    const float* k     = (const float*)d_in[1];
    const float* v     = (const float*)d_in[2];
    const void*  mask  = d_in[3];
    const float* wq    = (const float*)d_in[4];
    const float* bq    = (const float*)d_in[5];
    const float* wk    = (const float*)d_in[6];
    const float* bk    = (const float*)d_in[7];
    const float* wv    = (const float*)d_in[8];
    const float* bv    = (const float*)d_in[9];
    const float* wo    = (const float*)d_in[10];
    const float* bo    = (const float*)d_in[11];
    const float* gamma = (const float*)d_in[12];
    const float* beta  = (const float*)d_in[13];

    char* ws = (char*)d_ws;
    constexpr size_t SZ_H = (size_t)4096 * 1024 * 2;   // 8 MiB (fp16 [4096][1024])
    constexpr size_t SZ_W = (size_t)1024 * 1024 * 2;   // 2 MiB (fp16 [1024][1024])
    size_t off = 256;
    int* flag = (int*)ws;
    _Float16* wqt = (_Float16*)(ws + off); off += SZ_W;
    _Float16* wkt = (_Float16*)(ws + off); off += SZ_W;
    _Float16* wvt = (_Float16*)(ws + off); off += SZ_W;
    _Float16* wot = (_Float16*)(ws + off); off += SZ_W;
    _Float16* qb  = (_Float16*)(ws + off); off += SZ_H;   // qb,kb,vb contiguous
    _Float16* kb  = (_Float16*)(ws + off); off += SZ_H;
    _Float16* vb  = (_Float16*)(ws + off); off += SZ_H;
    _Float16* Qh  = (_Float16*)(ws + off); off += SZ_H;   // Qh,Kh,Vh contiguous
    _Float16* Kh  = (_Float16*)(ws + off); off += SZ_H;
    _Float16* Vh  = (_Float16*)(ws + off); off += SZ_H;
    _Float16* Vt  = (_Float16*)(ws + off); off += SZ_H;
    _Float16* mb  = (_Float16*)(ws + off); off += (size_t)2 * 2048 * 2048 * 2;
    _Float16* ctx = qb;        // reuse: qb dead after Q projection
    float*    y   = (float*)kb; // reuse: kb+vb (16 MiB) dead after K/V projections

    mask_detect_kernel<<<1, 256, 0, stream>>>((const unsigned int*)mask, flag);
    cast_kernel<<<4096, 256, 0, stream>>>(q, qb);
    cast_kernel<<<4096, 256, 0, stream>>>(k, kb);
    cast_kernel<<<4096, 256, 0, stream>>>(v, vb);
    dim3 tb(32, 8);
    wtrans_kernel<<<dim3(32, 32), tb, 0, stream>>>(wq, wqt);
    wtrans_kernel<<<dim3(32, 32), tb, 0, stream>>>(wk, wkt);
    wtrans_kernel<<<dim3(32, 32), tb, 0, stream>>>(wv, wvt);
    wtrans_kernel<<<dim3(32, 32), tb, 0, stream>>>(wo, wot);
    mask_bias_kernel<<<8192, 256, 0, stream>>>(mask, flag, mb);

    gemm_qkv_kernel<<<dim3(32, 8, 3), 256, 0, stream>>>(qb, wqt, bq, bk, bv, Qh);
    vtrans_kernel<<<dim3(2, 64, 32), tb, 0, stream>>>(Vh, Vt);
    attn_kernel<<<dim3(32, 32), 256, 0, stream>>>(Qh, Kh, Vt, mb, ctx);
    gemm_out_kernel<<<dim3(32, 8), 256, 0, stream>>>(ctx, wot, bo, q, y);
    ln_kernel<<<4096, 256, 0, stream>>>(y, gamma, beta, (float*)d_out);
}

// Round 6
// 195.654 us; speedup vs baseline: 1.1381x; 1.1381x over previous
//
#include <hip/hip_runtime.h>
#include <hip/hip_fp16.h>
#include <math.h>

// ---------------------------------------------------------------------------
// Fused transformer block: QKV proj -> masked MHA -> out proj + residual -> LN
// B=2, S=2048, D=1024, H=16, hd=64.  All GEMM/attention compute in fp16 MFMA
// with fp32 accumulation; final output fp32.
// ---------------------------------------------------------------------------

typedef _Float16 half8 __attribute__((ext_vector_type(8)));
typedef _Float16 half4v __attribute__((ext_vector_type(4)));
typedef float f32x4 __attribute__((ext_vector_type(4)));

#define MFMA16(a, b, c) __builtin_amdgcn_mfma_f32_16x16x32_f16((a), (b), (c), 0, 0, 0)

static __device__ __forceinline__ half8 cvt8(float4 a, float4 b) {
    half8 h;
    h[0] = (_Float16)a.x; h[1] = (_Float16)a.y; h[2] = (_Float16)a.z; h[3] = (_Float16)a.w;
    h[4] = (_Float16)b.x; h[5] = (_Float16)b.y; h[6] = (_Float16)b.z; h[7] = (_Float16)b.w;
    return h;
}

// ---------------------------------------------------------------------------
// Mask dtype detection (int32 vs byte bool): any packed word >1 => byte mode.
// ---------------------------------------------------------------------------
__global__ void mask_detect_kernel(const unsigned int* __restrict__ m, int* __restrict__ flag) {
    __shared__ int any;
    if (threadIdx.x == 0) any = 0;
    __syncthreads();
    unsigned v = 0;
#pragma unroll
    for (int i = 0; i < 8; ++i) v |= m[threadIdx.x + i * 256];
    if (v > 1u) atomicOr(&any, 1);
    __syncthreads();
    if (threadIdx.x == 0) *flag = any;
}

// mask -> additive fp16 bias (0 or -60000), [B][S][S]
__global__ void mask_bias_kernel(const void* __restrict__ mask, const int* __restrict__ flag,
                                 _Float16* __restrict__ mb) {
    const int i = (blockIdx.x * 256 + threadIdx.x) * 4;
    const bool bytemode = (*flag != 0);
    int v0, v1, v2, v3;
    if (bytemode) {
        const unsigned int w = *(const unsigned int*)((const unsigned char*)mask + i);
        v0 = w & 0xff; v1 = (w >> 8) & 0xff; v2 = (w >> 16) & 0xff; v3 = (w >> 24) & 0xff;
    } else {
        const int4 w = *(const int4*)((const int*)mask + i);
        v0 = w.x; v1 = w.y; v2 = w.z; v3 = w.w;
    }
    const _Float16 NEG = (_Float16)(-60000.0f);
    const _Float16 ZER = (_Float16)(0.0f);
    half4v o = { v0 ? NEG : ZER, v1 ? NEG : ZER, v2 ? NEG : ZER, v3 ? NEG : ZER };
    *(half4v*)(mb + i) = o;
}

// W[k][n] fp32 -> Wt[n][k] fp16 (transposed cast), 32x32 tiles
__global__ void wtrans_kernel(const float* __restrict__ W, _Float16* __restrict__ Wt) {
    __shared__ float t[32][33];
    const int tx = threadIdx.x, ty = threadIdx.y;
    const int n0 = blockIdx.x * 32, k0 = blockIdx.y * 32;
#pragma unroll
    for (int i = 0; i < 4; ++i)
        t[ty + i * 8][tx] = W[(size_t)(k0 + ty + i * 8) * 1024 + n0 + tx];
    __syncthreads();
#pragma unroll
    for (int i = 0; i < 4; ++i)
        Wt[(size_t)(n0 + ty + i * 8) * 1024 + k0 + tx] = (_Float16)t[tx][ty + i * 8];
}

// Vh[bh][s][d] -> Vt[bh][d][s], 32x32 tiles
__global__ void vtrans_kernel(const _Float16* __restrict__ Vh, _Float16* __restrict__ Vt) {
    __shared__ _Float16 t[32][33];
    const int tx = threadIdx.x, ty = threadIdx.y;
    const int d0 = blockIdx.x * 32, s0 = blockIdx.y * 32, bh = blockIdx.z;
    const _Float16* src = Vh + (size_t)bh * 2048 * 64;
    _Float16* dst = Vt + (size_t)bh * 64 * 2048;
#pragma unroll
    for (int i = 0; i < 4; ++i)
        t[ty + i * 8][tx] = src[(size_t)(s0 + ty + i * 8) * 64 + d0 + tx];
    __syncthreads();
#pragma unroll
    for (int i = 0; i < 4; ++i)
        dst[(size_t)(d0 + ty + i * 8) * 2048 + s0 + tx] = t[tx][ty + i * 8];
}

// ---------------------------------------------------------------------------
// QKV projection GEMM, reg-staged dbuf (round-4 proven) + fused fp32->fp16
// cast on the A operand (reads raw q/k/v fp32). grid.z selects q/k/v.
// 128x128 tile, BK=32, 4 waves. Epilogue: + bias, head layout [b,h,s,d] fp16.
// ---------------------------------------------------------------------------
__global__ __launch_bounds__(256) void gemm_qkv_kernel(
    const float* __restrict__ Aq, const float* __restrict__ Ak, const float* __restrict__ Av,
    const _Float16* __restrict__ Btbase,
    const float* __restrict__ bq, const float* __restrict__ bk, const float* __restrict__ bv,
    _Float16* __restrict__ Hbase) {
    constexpr int K = 1024;
    const int z = blockIdx.z;
    const float* A = (z == 0) ? Aq : ((z == 1) ? Ak : Av);
    const _Float16* Bt = Btbase + (size_t)z * 1024 * 1024;
    const float* bias = (z == 0) ? bq : ((z == 1) ? bk : bv);
    _Float16* outh = Hbase + (size_t)z * 32 * 2048 * 64;

    __shared__ __align__(16) _Float16 As[128 * 32];
    __shared__ __align__(16) _Float16 Bs[128 * 32];
    const int tid = threadIdx.x;
    const int mBase = blockIdx.x * 128, nBase = blockIdx.y * 128;
    const int r0 = tid >> 2, c0 = (tid & 3) * 8;
    const float* gA = A + (size_t)(mBase + r0) * K + c0;
    const _Float16* gB = Bt + (size_t)(nBase + r0) * K + c0;
    const int lane = tid & 63, wid = tid >> 6;
    const int wm = (wid >> 1) * 64, wn = (wid & 1) * 64;
    const int fr = lane & 15, fg = lane >> 4;

    f32x4 acc[4][4] = {};
    float4 a00 = *(const float4*)(gA);
    float4 a01 = *(const float4*)(gA + 4);
    float4 a10 = *(const float4*)(gA + 64 * K);
    float4 a11 = *(const float4*)(gA + 64 * K + 4);
    half8 rb0 = *(const half8*)(gB);
    half8 rb1 = *(const half8*)(gB + 64 * K);
    for (int kt = 0; kt < K / 32; ++kt) {
        __syncthreads();
        *(half8*)&As[tid * 8] = cvt8(a00, a01);
        *(half8*)&As[tid * 8 + 2048] = cvt8(a10, a11);
        *(half8*)&Bs[tid * 8] = rb0;
        *(half8*)&Bs[tid * 8 + 2048] = rb1;
        __syncthreads();
        if (kt + 1 < K / 32) {
            const int k1 = (kt + 1) * 32;
            a00 = *(const float4*)(gA + k1);
            a01 = *(const float4*)(gA + k1 + 4);
            a10 = *(const float4*)(gA + 64 * K + k1);
            a11 = *(const float4*)(gA + 64 * K + k1 + 4);
            rb0 = *(const half8*)(gB + k1);
            rb1 = *(const half8*)(gB + 64 * K + k1);
        }
        half8 af[4], bfv[4];
#pragma unroll
        for (int i = 0; i < 4; ++i) af[i] = *(const half8*)&As[(wm + i * 16 + fr) * 32 + fg * 8];
#pragma unroll
        for (int i = 0; i < 4; ++i) bfv[i] = *(const half8*)&Bs[(wn + i * 16 + fr) * 32 + fg * 8];
#pragma unroll
        for (int mi = 0; mi < 4; ++mi)
#pragma unroll
            for (int ni = 0; ni < 4; ++ni)
                acc[mi][ni] = MFMA16(af[mi], bfv[ni], acc[mi][ni]);
    }
#pragma unroll
    for (int mi = 0; mi < 4; ++mi)
#pragma unroll
        for (int ni = 0; ni < 4; ++ni)
#pragma unroll
            for (int j = 0; j < 4; ++j) {
                const int row = mBase + wm + mi * 16 + fg * 4 + j;  // 0..4095
                const int col = nBase + wn + ni * 16 + fr;          // 0..1023
                const float v = acc[mi][ni][j] + bias[col];
                const int b = row >> 11, s = row & 2047, h = col >> 6, d = col & 63;
                outh[(((size_t)(b * 16 + h) * 2048) + s) * 64 + d] = (_Float16)v;
            }
}

// Output projection GEMM: y = ctx @ Wo + bo + residual (fp32 out)
__global__ __launch_bounds__(256) void gemm_out_kernel(
    const _Float16* __restrict__ A, const _Float16* __restrict__ Bt,
    const float* __restrict__ bias, const float* __restrict__ resid,
    float* __restrict__ outf) {
    constexpr int K = 1024;
    __shared__ __align__(16) _Float16 As[128 * 32];
    __shared__ __align__(16) _Float16 Bs[128 * 32];
    const int tid = threadIdx.x;
    const int mBase = blockIdx.x * 128, nBase = blockIdx.y * 128;
    const int r0 = tid >> 2, c0 = (tid & 3) * 8;
    const _Float16* gA = A + (size_t)(mBase + r0) * K + c0;
    const _Float16* gB = Bt + (size_t)(nBase + r0) * K + c0;
    const int lane = tid & 63, wid = tid >> 6;
    const int wm = (wid >> 1) * 64, wn = (wid & 1) * 64;
    const int fr = lane & 15, fg = lane >> 4;

    f32x4 acc[4][4] = {};
    half8 ra0 = *(const half8*)(gA);
    half8 ra1 = *(const half8*)(gA + 64 * K);
    half8 rb0 = *(const half8*)(gB);
    half8 rb1 = *(const half8*)(gB + 64 * K);
    for (int kt = 0; kt < K / 32; ++kt) {
        __syncthreads();
        *(half8*)&As[tid * 8] = ra0;
        *(half8*)&As[tid * 8 + 2048] = ra1;
        *(half8*)&Bs[tid * 8] = rb0;
        *(half8*)&Bs[tid * 8 + 2048] = rb1;
        __syncthreads();
        if (kt + 1 < K / 32) {
            const int k1 = (kt + 1) * 32;
            ra0 = *(const half8*)(gA + k1);
            ra1 = *(const half8*)(gA + 64 * K + k1);
            rb0 = *(const half8*)(gB + k1);
            rb1 = *(const half8*)(gB + 64 * K + k1);
        }
        half8 af[4], bfv[4];
#pragma unroll
        for (int i = 0; i < 4; ++i) af[i] = *(const half8*)&As[(wm + i * 16 + fr) * 32 + fg * 8];
#pragma unroll
        for (int i = 0; i < 4; ++i) bfv[i] = *(const half8*)&Bs[(wn + i * 16 + fr) * 32 + fg * 8];
#pragma unroll
        for (int mi = 0; mi < 4; ++mi)
#pragma unroll
            for (int ni = 0; ni < 4; ++ni)
                acc[mi][ni] = MFMA16(af[mi], bfv[ni], acc[mi][ni]);
    }
#pragma unroll
    for (int mi = 0; mi < 4; ++mi)
#pragma unroll
        for (int ni = 0; ni < 4; ++ni)
#pragma unroll
            for (int j = 0; j < 4; ++j) {
                const int row = mBase + wm + mi * 16 + fg * 4 + j;
                const int col = nBase + wn + ni * 16 + fr;
                const size_t idx = (size_t)row * 1024 + col;
                outf[idx] = acc[mi][ni][j] + bias[col] + resid[idx];
            }
}

// ---------------------------------------------------------------------------
// Flash attention v5: KT=128, single-buffered LDS + T14 reg-staged split
// (loads issued right after buf-ready barrier, ds_writes after end-of-compute
// barrier). K rows staged PERMUTED: position p holds true K row
// k = (p&15)*8 + (p>>4), so each lane's 32 scores have contiguous true-k
// fg*32+[0,32): mask = 4 coalesced half8, P-pack = 4 half8 at true-k.
// V staging and PV pairing stay natural (permutation absorbed by K source
// addressing only; D-row k_true = fg*32 + j*8 + s, pack w[m][e] = p[e][m]).
// LDS 48KB -> 3 blocks/CU. Softmax: log2-domain Q pre-scale, defer-max,
// l via ones-MFMA (round-5 machinery).
// ---------------------------------------------------------------------------
__global__ __launch_bounds__(256) void attn_kernel(
    const _Float16* __restrict__ Qh, const _Float16* __restrict__ Kh,
    const _Float16* __restrict__ Vt, const _Float16* __restrict__ mb,
    _Float16* __restrict__ ctx) {
    constexpr int S = 2048;
    constexpr int KT = 128;
    __shared__ __align__(16) _Float16 Ks[128][64];    // 16 KiB, row-swizzled
    __shared__ __align__(16) _Float16 Vs[64][128];    // 16 KiB, row-swizzled
    __shared__ __align__(16) _Float16 Pl[4][16][128]; // 16 KiB, swizzled, per-wave
    const int tid = threadIdx.x, lane = tid & 63, wid = tid >> 6;
    const int fr = lane & 15, fg = lane >> 4;
    const int bh = blockIdx.y;
    const int b = bh >> 4, h = bh & 15;
    const int q0 = blockIdx.x * 64 + wid * 16;
    const int q = q0 + fr;
    const _Float16* Qp = Qh + (size_t)bh * S * 64;
    const _Float16* Kp = Kh + (size_t)bh * S * 64;
    const _Float16* Vp = Vt + (size_t)bh * 64 * S;
    const _Float16* mrow = mb + ((size_t)b * S + q) * S + fg * 32;

    // Q as B-fragment, pre-scaled into log2-domain: 0.125 * log2(e)
    half8 qf0 = *(const half8*)(Qp + (size_t)q * 64 + fg * 8);
    half8 qf1 = *(const half8*)(Qp + (size_t)q * 64 + 32 + fg * 8);
    const _Float16 QSC = (_Float16)0.18033688f;
#pragma unroll
    for (int i = 0; i < 8; ++i) { qf0[i] = qf0[i] * QSC; qf1[i] = qf1[i] * QSC; }
    half8 ones8;
#pragma unroll
    for (int i = 0; i < 8; ++i) ones8[i] = (_Float16)1.0f;

    // staging geometry
    const int kCol = (tid & 7) * 8;     // halfs within K row (64)
    const int vCol = (tid & 15) * 8;    // halfs within V row (128)
    int kTrue[4], kW[4], vRow[4], vW[4];
#pragma unroll
    for (int n = 0; n < 4; ++n) {
        const int p = (tid >> 3) + 32 * n;               // K tile position 0..127
        kTrue[n] = ((p & 15) << 3) | (p >> 4);           // true K row in tile
        kW[n] = p * 64 + (kCol ^ ((p & 7) << 3));
        const int d = (tid >> 4) + 16 * n;               // V row 0..63
        vRow[n] = d;
        vW[n] = d * 128 + (vCol ^ ((d & 15) << 3));
    }
    const int swzK = (fr & 7) << 3;   // read swizzle for K and Pl
    const int swzV = fr << 3;         // read swizzle for V rows (d&15 == fr)

    f32x4 acc[4] = {};   // acc[n][j] = ctx[q][d = n*16 + fg*4 + j]
    f32x4 accl = {};     // ones-MFMA row sums (all comps equal)
    float m_r = -1e30f;
    const float TH = 11.5f;

    // ---- prologue: load tile 0 into regs ----
    half8 sK[4], sV[4], mcur[4], mnx[4];
#pragma unroll
    for (int n = 0; n < 4; ++n) {
        sK[n] = *(const half8*)(Kp + (size_t)kTrue[n] * 64 + kCol);
        sV[n] = *(const half8*)(Vp + (size_t)vRow[n] * S + vCol);
        mcur[n] = *(const half8*)(mrow + n * 8);
    }

    _Float16* Pw = &Pl[wid][0][0];

    for (int t = 0; t < 16; ++t) {
        __syncthreads();   // all waves done reading the buffer (prev iter)
#pragma unroll
        for (int n = 0; n < 4; ++n) {
            *(half8*)&Ks[0][kW[n]] = sK[n];
            *(half8*)&Vs[0][vW[n]] = sV[n];
        }
        __syncthreads();   // buffer ready

        // ---- issue next-tile global loads (consumed at next iter's writes) ----
        const int kn = (t < 15) ? (t + 1) * KT : t * KT;
#pragma unroll
        for (int n = 0; n < 4; ++n) {
            sK[n] = *(const half8*)(Kp + (size_t)(kn + kTrue[n]) * 64 + kCol);
            sV[n] = *(const half8*)(Vp + (size_t)vRow[n] * S + kn + vCol);
            mnx[n] = *(const half8*)(mrow + kn + n * 8);
        }

        // ---- QK^T swapped: A = K positions, B = Q -> D[pos][q] ----
        f32x4 tt[8];
#pragma unroll
        for (int s = 0; s < 8; ++s) {
            const int p = s * 16 + fr;
            const half8 ka0 = *(const half8*)&Ks[0][p * 64 + ((fg * 8) ^ swzK)];
            const half8 ka1 = *(const half8*)&Ks[0][p * 64 + ((32 + fg * 8) ^ swzK)];
            f32x4 z = {};
            tt[s] = MFMA16(ka0, qf0, z);
            tt[s] = MFMA16(ka1, qf1, tt[s]);
        }

        // ---- scores: lane's true k = fg*32 + j*8 + s -> mask mcur[j][s] ----
        float pmax = -1e30f;
#pragma unroll
        for (int s = 0; s < 8; ++s)
#pragma unroll
            for (int j = 0; j < 4; ++j) {
                tt[s][j] += (float)mcur[j][s];
                pmax = fmaxf(pmax, tt[s][j]);
            }
        if (__any(pmax > m_r + TH)) {
            pmax = fmaxf(pmax, __shfl_xor(pmax, 16));
            pmax = fmaxf(pmax, __shfl_xor(pmax, 32));
            const float mnew = fmaxf(m_r, pmax);
            const float scf = exp2f(m_r - mnew);
#pragma unroll
            for (int n = 0; n < 4; ++n)
#pragma unroll
                for (int j = 0; j < 4; ++j) acc[n][j] *= scf;
#pragma unroll
            for (int j = 0; j < 4; ++j) accl[j] *= scf;
            m_r = mnew;
        }
#pragma unroll
        for (int s = 0; s < 8; ++s)
#pragma unroll
            for (int j = 0; j < 4; ++j)
                tt[s][j] = exp2f(tt[s][j] - m_r);

        // ---- pack P -> Pl at TRUE k (w[m][e] = p[e][m]), swizzled ----
#pragma unroll
        for (int m = 0; m < 4; ++m) {
            half8 w;
#pragma unroll
            for (int e = 0; e < 8; ++e) w[e] = (_Float16)tt[e][m];
            *(half8*)&Pw[fr * 128 + ((fg * 32 + m * 8) ^ swzK)] = w;
        }

        // ---- PV swapped: A = V rows (d), B = P^T -> D[d][q]; l via ones ----
#pragma unroll
        for (int c = 0; c < 4; ++c) {
            const half8 pa = *(const half8*)&Pw[fr * 128 + ((c * 32 + fg * 8) ^ swzK)];
            accl = MFMA16(ones8, pa, accl);
#pragma unroll
            for (int n = 0; n < 4; ++n) {
                const int d = n * 16 + fr;
                const half8 vb = *(const half8*)&Vs[0][d * 128 + ((c * 32 + fg * 8) ^ swzV)];
                acc[n] = MFMA16(vb, pa, acc[n]);
            }
        }
#pragma unroll
        for (int n = 0; n < 4; ++n) mcur[n] = mnx[n];
    }

    const float inv = 1.0f / accl[0];
#pragma unroll
    for (int n = 0; n < 4; ++n) {
        half4v o = { (_Float16)(acc[n][0] * inv), (_Float16)(acc[n][1] * inv),
                     (_Float16)(acc[n][2] * inv), (_Float16)(acc[n][3] * inv) };
        *(half4v*)&ctx[((size_t)b * 2048 + q) * 1024 + h * 64 + n * 16 + fg * 4] = o;
    }
}

// LayerNorm over D=1024, one block per row
__global__ __launch_bounds__(256) void ln_kernel(
    const float* __restrict__ y, const float* __restrict__ gamma,
    const float* __restrict__ beta, float* __restrict__ out) {
    const int row = blockIdx.x, tid = threadIdx.x;
    const size_t base = (size_t)row * 1024 + tid * 4;
    const float4 v = *(const float4*)(y + base);
    float s = v.x + v.y + v.z + v.w;
    float ss = v.x * v.x + v.y * v.y + v.z * v.z + v.w * v.w;
#pragma unroll
    for (int o = 1; o < 64; o <<= 1) {
        s += __shfl_xor(s, o, 64);
        ss += __shfl_xor(ss, o, 64);
    }
    __shared__ float red[8];
    const int wid = tid >> 6;
    if ((tid & 63) == 0) { red[wid] = s; red[wid + 4] = ss; }
    __syncthreads();
    s = red[0] + red[1] + red[2] + red[3];
    ss = red[4] + red[5] + red[6] + red[7];
    const float mu = s * (1.0f / 1024.0f);
    const float var = ss * (1.0f / 1024.0f) - mu * mu;
    const float rstd = rsqrtf(var + 1e-5f);
    const float4 g = *(const float4*)(gamma + tid * 4);
    const float4 bt = *(const float4*)(beta + tid * 4);
    float4 o;
    o.x = (v.x - mu) * rstd * g.x + bt.x;
    o.y = (v.y - mu) * rstd * g.y + bt.y;
    o.z = (v.z - mu) * rstd * g.z + bt.z;
    o.w = (v.w - mu) * rstd * g.w + bt.w;
    *(float4*)(out + base) = o;
}

// ---------------------------------------------------------------------------
extern "C" void kernel_launch(void* const* d_in, const int* in_sizes, int n_in,
                              void* d_out, int out_size, void* d_ws, size_t ws_size,
                              hipStream_t stream) {
    (void)in_sizes; (void)n_in; (void)out_size; (void)ws_size;
    const float* q     = (const float*)d_in[0];
    const float* k     = (const float*)d_in[1];
    const float* v     = (const float*)d_in[2];
    const void*  mask  = d_in[3];
    const float* wq    = (const float*)d_in[4];
    const float* bq    = (const float*)d_in[5];
    const float* wk    = (const float*)d_in[6];
    const float* bk    = (const float*)d_in[7];
    const float* wv    = (const float*)d_in[8];
    const float* bv    = (const float*)d_in[9];
    const float* wo    = (const float*)d_in[10];
    const float* bo    = (const float*)d_in[11];
    const float* gamma = (const float*)d_in[12];
    const float* beta  = (const float*)d_in[13];

    char* ws = (char*)d_ws;
    constexpr size_t SZ_H = (size_t)4096 * 1024 * 2;   // 8 MiB (fp16 [4096][1024])
    constexpr size_t SZ_W = (size_t)1024 * 1024 * 2;   // 2 MiB (fp16 [1024][1024])
    size_t off = 256;
    int* flag = (int*)ws;
    _Float16* wqt = (_Float16*)(ws + off); off += SZ_W;
    _Float16* wkt = (_Float16*)(ws + off); off += SZ_W;
    _Float16* wvt = (_Float16*)(ws + off); off += SZ_W;
    _Float16* wot = (_Float16*)(ws + off); off += SZ_W;
    _Float16* scratchA = (_Float16*)(ws + off); off += SZ_H;  // ctx lives here
    _Float16* scratchB = (_Float16*)(ws + off); off += SZ_H;  // y lives here (fp32, 16MiB = 2 slots)
    _Float16* scratchC = (_Float16*)(ws + off); off += SZ_H;
    _Float16* Qh  = (_Float16*)(ws + off); off += SZ_H;   // Qh,Kh,Vh contiguous
    _Float16* Kh  = (_Float16*)(ws + off); off += SZ_H;
    _Float16* Vh  = (_Float16*)(ws + off); off += SZ_H;
    _Float16* Vt  = (_Float16*)(ws + off); off += SZ_H;
    _Float16* mb  = (_Float16*)(ws + off); off += (size_t)2 * 2048 * 2048 * 2;
    _Float16* ctx = scratchA;
    float*    y   = (float*)scratchB;   // uses scratchB+scratchC (16 MiB)

    mask_detect_kernel<<<1, 256, 0, stream>>>((const unsigned int*)mask, flag);
    dim3 tb(32, 8);
    wtrans_kernel<<<dim3(32, 32), tb, 0, stream>>>(wq, wqt);
    wtrans_kernel<<<dim3(32, 32), tb, 0, stream>>>(wk, wkt);
    wtrans_kernel<<<dim3(32, 32), tb, 0, stream>>>(wv, wvt);
    wtrans_kernel<<<dim3(32, 32), tb, 0, stream>>>(wo, wot);
    mask_bias_kernel<<<8192, 256, 0, stream>>>(mask, flag, mb);

    gemm_qkv_kernel<<<dim3(32, 8, 3), 256, 0, stream>>>(q, k, v, wqt, bq, bk, bv, Qh);
    vtrans_kernel<<<dim3(2, 64, 32), tb, 0, stream>>>(Vh, Vt);
    attn_kernel<<<dim3(32, 32), 256, 0, stream>>>(Qh, Kh, Vt, mb, ctx);
    gemm_out_kernel<<<dim3(32, 8), 256, 0, stream>>>(ctx, wot, bo, q, y);
    ln_kernel<<<4096, 256, 0, stream>>>(y, gamma, beta, (float*)d_out);
}